// Round 4
// baseline (436.522 us; speedup 1.0000x reference)
//
#include <hip/hip_runtime.h>
#include <hip/hip_bf16.h>

#define B_   512
#define N_   64
#define M_   12
#define F_   64
#define NF_  41
#define NODES (B_*N_)      /* 32768 */
#define ROWS  (NODES*M_)   /* 393216 */
#define NPB   8            /* nodes per block in k_gemm */
#define RPB   (NPB*M_)     /* 96 rows per block */
#define GBLK  (NODES/NPB)  /* 4096 gemm blocks */
#define ABLK  1024         /* act blocks */
#define KTOT  169
#define ASTR  200          /* LDS A-row stride in bf16 */
#define CSTR  136          /* LDS C-row stride in bf16 (16B-aligned rows) */

typedef __bf16 bf16x8 __attribute__((ext_vector_type(8)));
typedef float  f32x4  __attribute__((ext_vector_type(4)));

/* workspace layout (bytes):
   [0,64):          float scal[4]  (mu1, inv1, mu2, inv2)
   [1024, +65536):  float part1[4][4096]   (s1, ss1, cnz1, cm1 per gemm block)
   [66560, +16384): float part2[3][1024]   (s2, ss2, c2 per act block) + pad
   [82944, +49152): bf16 Wf — fragment-ordered W
   [132096, +ROWS*128*2): bf16 total_gated (masked)                  */
#define P1_OFF 1024
#define P2_OFF 66560
#define WF_OFF 82944
#define X_OFF  132096

__device__ __forceinline__ float waveReduce(float v) {
#pragma unroll
  for (int off = 32; off > 0; off >>= 1) v += __shfl_down(v, off, 64);
  return v;
}

/* ------- K0: W (fp32, row-major 169x128) -> fragment-ordered bf16 ------- */
__global__ void k_wprep(const float* __restrict__ W, __bf16* __restrict__ Wf) {
  int t = blockIdx.x * 256 + threadIdx.x;
  if (t >= 6 * 8 * 64) return;
  int lane = t & 63, nt = (t >> 6) & 7, kc = t >> 9;
  int n  = nt * 16 + (lane & 15);
  int k0 = kc * 32 + (lane >> 4) * 8;
  bf16x8 v;
#pragma unroll
  for (int j = 0; j < 8; j++) {
    int k = k0 + j;
    v[j] = (k < KTOT) ? (__bf16)W[k * 128 + n] : (__bf16)0.f;
  }
  *reinterpret_cast<bf16x8*>(&Wf[(size_t)t * 8]) = v;
}

/* ---------------- K1: gather + concat + MFMA GEMM + mask + partial stats ------- */
__global__ __launch_bounds__(256, 4) void k_gemm(
    const float* __restrict__ atom, const float* __restrict__ nbr,
    const int* __restrict__ idx, const int* __restrict__ mask,
    const __bf16* __restrict__ Wf, const float* __restrict__ bias,
    float* __restrict__ part1, __bf16* __restrict__ xout)
{
  __shared__ __bf16 As[RPB * ASTR];   // 38400 B; C-tile (96x136 bf16) overlays it later
  __shared__ int    idx_s[RPB];
  __shared__ float  red[4][4];

  const int tid = threadIdx.x;
  const int g0  = blockIdx.x * NPB;
  const int bb  = (g0 >> 6) << 6;     // b * N_  (block never crosses a batch)

  if (tid < RPB) idx_s[tid] = idx[g0 * M_ + tid];
  __syncthreads();

  // stage own-atom part, k in [0,64)
  for (int e = tid; e < RPB * 16; e += 256) {
    int r = e >> 4, k4 = e & 15;
    int node = r / M_;
    float4 v = *(const float4*)&atom[(size_t)(g0 + node) * F_ + k4 * 4];
    __bf16 h[4] = {(__bf16)v.x, (__bf16)v.y, (__bf16)v.z, (__bf16)v.w};
    *reinterpret_cast<uint2*>(&As[r * ASTR + k4 * 4]) = *reinterpret_cast<uint2*>(h);
  }
  // stage gathered-atom part, k in [64,128)
  for (int e = tid; e < RPB * 16; e += 256) {
    int r = e >> 4, k4 = e & 15;
    float4 v = *(const float4*)&atom[(size_t)(bb + idx_s[r]) * F_ + k4 * 4];
    __bf16 h[4] = {(__bf16)v.x, (__bf16)v.y, (__bf16)v.z, (__bf16)v.w};
    *reinterpret_cast<uint2*>(&As[r * ASTR + 64 + k4 * 4]) = *reinterpret_cast<uint2*>(h);
  }
  // stage nbr_fea part, k in [128,169)
  for (int e = tid; e < RPB * NF_; e += 256) {
    int r = e / NF_, k = e - r * NF_;
    As[r * ASTR + 128 + k] = (__bf16)nbr[(size_t)(g0 * M_ + r) * NF_ + k];
  }
  // zero pad k in [169,192)
  for (int e = tid; e < RPB * 32; e += 256) {
    int r = e >> 5, k = 168 + (e & 31);
    if (k >= KTOT) As[r * ASTR + k] = (__bf16)0.f;
  }
  __syncthreads();

  const int w    = tid >> 6;          // wave id: owns nt = {2w, 2w+1}
  const int lane = tid & 63;
  const int nlo  = lane & 15;
  const int quad = lane >> 4;

  f32x4 acc[6][2];
#pragma unroll
  for (int mt = 0; mt < 6; mt++)
#pragma unroll
    for (int j = 0; j < 2; j++) acc[mt][j] = (f32x4){0.f, 0.f, 0.f, 0.f};

#pragma unroll
  for (int kc = 0; kc < 6; kc++) {
    bf16x8 bf[2];
#pragma unroll
    for (int j = 0; j < 2; j++) {
      int nt = 2 * w + j;
      bf[j] = *reinterpret_cast<const bf16x8*>(&Wf[(size_t)(((kc * 8 + nt) * 64) + lane) * 8]);
    }
#pragma unroll
    for (int mt = 0; mt < 6; mt++) {
      bf16x8 af = *reinterpret_cast<const bf16x8*>(
          &As[(mt * 16 + nlo) * ASTR + kc * 32 + quad * 8]);
#pragma unroll
      for (int j = 0; j < 2; j++)
        acc[mt][j] = __builtin_amdgcn_mfma_f32_16x16x32_bf16(af, bf[j], acc[mt][j], 0, 0, 0);
    }
  }

  // ---- dump C tile (bias-added, bf16) into LDS for vectorized masked store ----
  float bv[2];
#pragma unroll
  for (int j = 0; j < 2; j++) bv[j] = bias[(2 * w + j) * 16 + nlo];

  __syncthreads();                    // all A-frag reads done; safe to overlay
  __bf16* Cs = As;
#pragma unroll
  for (int mt = 0; mt < 6; mt++)
#pragma unroll
    for (int reg = 0; reg < 4; reg++)
#pragma unroll
      for (int j = 0; j < 2; j++) {
        int row = mt * 16 + quad * 4 + reg;
        int col = (2 * w + j) * 16 + nlo;
        Cs[row * CSTR + col] = (__bf16)(acc[mt][j][reg] + bv[j]);
      }
  __syncthreads();

  // ---- vectorized mask + stats + store: 6 chunks of 8 per thread ----
  float s = 0.f, ss = 0.f, cz = 0.f, cm = 0.f;
#pragma unroll
  for (int i = 0; i < 6; i++) {
    int ch = tid + i * 256;           // 0..1535
    int row = ch >> 4, c = ch & 15;
    size_t grow = (size_t)(g0 * M_) + row;
    bf16x8 yv = *reinterpret_cast<const bf16x8*>(&Cs[row * CSTR + c * 8]);
    const int4 mA = *(const int4*)&mask[grow * 128 + c * 8];
    const int4 mB = *(const int4*)&mask[grow * 128 + c * 8 + 4];
    int mv[8] = {mA.x, mA.y, mA.z, mA.w, mB.x, mB.y, mB.z, mB.w};
#pragma unroll
    for (int j = 0; j < 8; j++) {
      float y = (float)yv[j];
      if (!mv[j]) { y = 0.f; yv[j] = (__bf16)0.f; }
      s += y; ss += y * y;
      cz += (y != 0.f) ? 1.f : 0.f;
      cm += (float)mv[j];
    }
    *reinterpret_cast<bf16x8*>(&xout[grow * 128 + c * 8]) = yv;
  }

  float v0 = waveReduce(s), v1 = waveReduce(ss), v2 = waveReduce(cz), v3 = waveReduce(cm);
  if (lane == 0) { red[0][w] = v0; red[1][w] = v1; red[2][w] = v2; red[3][w] = v3; }
  __syncthreads();
  if (tid < 4)   // non-atomic partial store: no same-line RMW contention
    part1[tid * GBLK + blockIdx.x] =
        red[tid][0] + red[tid][1] + red[tid][2] + red[tid][3];
}

/* ------- R1: reduce part1 -> mu1, inv1 ------- */
__global__ __launch_bounds__(256) void k_red1(const float* __restrict__ part1,
                                              float* __restrict__ scal) {
  __shared__ double red[256][4];
  int t = threadIdx.x;
  double a[4] = {0.0, 0.0, 0.0, 0.0};
  for (int i = t; i < GBLK; i += 256)
#pragma unroll
    for (int q = 0; q < 4; q++) a[q] += (double)part1[q * GBLK + i];
#pragma unroll
  for (int q = 0; q < 4; q++) red[t][q] = a[q];
  __syncthreads();
  for (int s = 128; s > 0; s >>= 1) {
    if (t < s)
#pragma unroll
      for (int q = 0; q < 4; q++) red[t][q] += red[t + s][q];
    __syncthreads();
  }
  if (t == 0) {
    double S = red[0][0], SS = red[0][1], CNZ = red[0][2], CM = red[0][3];
    double mu = 0.0, var = 0.0;
    if (CNZ > 0.5) {
      mu = S / CNZ;
      var = (SS - 2.0 * mu * S + mu * mu * CM) / CNZ;
    }
    scal[0] = (float)mu;
    scal[1] = (float)(1.0 / sqrt(var + 1e-5));
  }
}

/* ------- K3: BN1-apply + sigmoid*softplus + sum over M + partial stats2 ------- */
__global__ __launch_bounds__(256) void k_act(
    const __bf16* __restrict__ x, const int* __restrict__ mask,
    const float* __restrict__ g1, const float* __restrict__ b1,
    const float* __restrict__ scal, float* __restrict__ part2,
    float* __restrict__ ns)
{
  __shared__ float red[3][4];
  int t = blockIdx.x * 256 + threadIdx.x;    // 0 .. NODES*8-1
  int g = t >> 3, o0 = (t & 7) * 8;

  float mu1 = scal[0], inv1 = scal[1];

  float kf[8], cf[8], kc[8], cc[8];
#pragma unroll
  for (int j = 0; j < 8; j++) {
    kf[j] = inv1 * g1[o0 + j];      cf[j] = b1[o0 + j]      - mu1 * kf[j];
    kc[j] = inv1 * g1[64 + o0 + j]; cc[j] = b1[64 + o0 + j] - mu1 * kc[j];
  }

  size_t base = (size_t)g * (M_ * 128) + o0;
  float ssum[8];
#pragma unroll
  for (int j = 0; j < 8; j++) ssum[j] = 0.f;

#pragma unroll
  for (int m = 0; m < M_; m++) {
    bf16x8 xf = *reinterpret_cast<const bf16x8*>(&x[base + m * 128]);
    bf16x8 xc = *reinterpret_cast<const bf16x8*>(&x[base + m * 128 + 64]);
#pragma unroll
    for (int j = 0; j < 8; j++) {
      float vf = (float)xf[j], vc = (float)xc[j];
      // x==0 <=> masked-out (stored exact 0); bn applies only where mask=1
      float yf = (vf != 0.f) ? fmaf(vf, kf[j], cf[j]) : 0.f;
      float yc = (vc != 0.f) ? fmaf(vc, kc[j], cc[j]) : 0.f;
      float sg = __builtin_amdgcn_rcpf(1.f + __expf(-yf));
      float sp = fmaxf(yc, 0.f) + __logf(1.f + __expf(-fabsf(yc)));
      ssum[j] += sg * sp;   // masked-out contributes sigmoid(0)*softplus(0), per ref
    }
  }

  const int4 mA = *(const int4*)&mask[(size_t)g * (M_ * 128) + o0];
  const int4 mB = *(const int4*)&mask[(size_t)g * (M_ * 128) + o0 + 4];
  int mn[8] = {mA.x, mA.y, mA.z, mA.w, mB.x, mB.y, mB.z, mB.w};
  float s = 0.f, ss2 = 0.f, c = 0.f;
  float v[8];
#pragma unroll
  for (int j = 0; j < 8; j++) {
    v[j] = mn[j] ? ssum[j] : 0.f;
    s += v[j]; ss2 += v[j] * v[j];
    c += (v[j] != 0.f) ? 1.f : 0.f;
  }
  *(float4*)&ns[(size_t)g * 64 + o0]     = (float4){v[0], v[1], v[2], v[3]};
  *(float4*)&ns[(size_t)g * 64 + o0 + 4] = (float4){v[4], v[5], v[6], v[7]};

  float v0 = waveReduce(s), v1 = waveReduce(ss2), v2 = waveReduce(c);
  int lane = threadIdx.x & 63, wid = threadIdx.x >> 6;
  if (lane == 0) { red[0][wid] = v0; red[1][wid] = v1; red[2][wid] = v2; }
  __syncthreads();
  if (threadIdx.x < 3)   // non-atomic partial store
    part2[threadIdx.x * ABLK + blockIdx.x] =
        red[threadIdx.x][0] + red[threadIdx.x][1] + red[threadIdx.x][2] + red[threadIdx.x][3];
}

/* ------- R2: reduce part2 -> mu2, inv2 ------- */
__global__ __launch_bounds__(256) void k_red2(const float* __restrict__ part2,
                                              float* __restrict__ scal) {
  __shared__ double red[256][3];
  int t = threadIdx.x;
  double a[3] = {0.0, 0.0, 0.0};
  for (int i = t; i < ABLK; i += 256)
#pragma unroll
    for (int q = 0; q < 3; q++) a[q] += (double)part2[q * ABLK + i];
#pragma unroll
  for (int q = 0; q < 3; q++) red[t][q] = a[q];
  __syncthreads();
  for (int s = 128; s > 0; s >>= 1) {
    if (t < s)
#pragma unroll
      for (int q = 0; q < 3; q++) red[t][q] += red[t + s][q];
    __syncthreads();
  }
  if (t == 0) {
    double S = red[0][0], SS = red[0][1], C = red[0][2];
    double mu = 0.0, var = 0.0;
    if (C > 0.5) {
      mu = S / C;
      var = (SS - 2.0 * mu * S + mu * mu * C) / C;
    }
    scal[2] = (float)mu;
    scal[3] = (float)(1.0 / sqrt(var + 1e-5));
  }
}

/* ---------------- K5: BN2-apply + residual softplus ---------------- */
__global__ __launch_bounds__(256) void k_out(
    const float* __restrict__ atom, const float* __restrict__ ns,
    const float* __restrict__ g2, const float* __restrict__ b2,
    const float* __restrict__ scal, float* __restrict__ out)
{
  int t = blockIdx.x * 256 + threadIdx.x;
  int g = t >> 3, o0 = (t & 7) * 8;
  float mu2 = scal[2], inv2 = scal[3];

  float4 n0 = *(const float4*)&ns[(size_t)g * 64 + o0];
  float4 n1 = *(const float4*)&ns[(size_t)g * 64 + o0 + 4];
  float4 a0 = *(const float4*)&atom[(size_t)g * 64 + o0];
  float4 a1 = *(const float4*)&atom[(size_t)g * 64 + o0 + 4];
  float nv[8] = {n0.x, n0.y, n0.z, n0.w, n1.x, n1.y, n1.z, n1.w};
  float av[8] = {a0.x, a0.y, a0.z, a0.w, a1.x, a1.y, a1.z, a1.w};
  float r[8];
#pragma unroll
  for (int j = 0; j < 8; j++) {
    r[j] = 0.f;
    if (nv[j] != 0.f) {   // ns != 0 <=> m_node == 1 (gated strictly > 0)
      float bn = (nv[j] - mu2) * inv2 * g2[o0 + j] + b2[o0 + j];
      float a = av[j] + bn;
      r[j] = fmaxf(a, 0.f) + __logf(1.f + __expf(-fabsf(a)));
    }
  }
  *(float4*)&out[(size_t)g * 64 + o0]     = (float4){r[0], r[1], r[2], r[3]};
  *(float4*)&out[(size_t)g * 64 + o0 + 4] = (float4){r[4], r[5], r[6], r[7]};
}

extern "C" void kernel_launch(void* const* d_in, const int* in_sizes, int n_in,
                              void* d_out, int out_size, void* d_ws, size_t ws_size,
                              hipStream_t stream)
{
  const float* atom = (const float*)d_in[0];
  const float* nbr  = (const float*)d_in[1];
  const float* W    = (const float*)d_in[2];
  const float* bias = (const float*)d_in[3];
  const float* g1   = (const float*)d_in[4];
  const float* b1   = (const float*)d_in[5];
  const float* g2   = (const float*)d_in[6];
  const float* b2   = (const float*)d_in[7];
  const int*   idx  = (const int*)d_in[8];
  const int*   mask = (const int*)d_in[9];
  float* out = (float*)d_out;

  char* ws = (char*)d_ws;
  float*  scal  = (float*)ws;
  float*  part1 = (float*)(ws + P1_OFF);
  float*  part2 = (float*)(ws + P2_OFF);
  __bf16* Wf    = (__bf16*)(ws + WF_OFF);
  __bf16* x     = (__bf16*)(ws + X_OFF);
  float* ns = out;   // reuse d_out: k_act writes all of it, k_out rewrites in place

  k_wprep<<<12, 256, 0, stream>>>(W, Wf);
  k_gemm<<<GBLK, 256, 0, stream>>>(atom, nbr, idx, mask, Wf, bias, part1, x);
  k_red1<<<1, 256, 0, stream>>>(part1, scal);
  k_act<<<(NODES * 8) / 256, 256, 0, stream>>>(x, mask, g1, b1, scal, part2, ns);
  k_red2<<<1, 256, 0, stream>>>(part2, scal);
  k_out<<<(NODES * 8) / 256, 256, 0, stream>>>(atom, ns, g2, b2, scal, out);
}

// Round 5
// 416.299 us; speedup vs baseline: 1.0486x; 1.0486x over previous
//
#include <hip/hip_runtime.h>
#include <hip/hip_bf16.h>

#define B_   512
#define N_   64
#define M_   12
#define F_   64
#define NF_  41
#define NODES (B_*N_)      /* 32768 */
#define ROWS  (NODES*M_)   /* 393216 */
#define NPB   4            /* nodes per block in k_gemm */
#define RPB   (NPB*M_)     /* 48 rows per block */
#define GBLK  (NODES/NPB)  /* 8192 gemm blocks */
#define ABLK  1024         /* act blocks */
#define KTOT  169
#define ASTR  200          /* LDS A-row stride in bf16 */
#define CSTR  136          /* LDS C-row stride in bf16 (16B-aligned rows) */

typedef __bf16 bf16x8 __attribute__((ext_vector_type(8)));
typedef float  f32x4  __attribute__((ext_vector_type(4)));

/* workspace layout (bytes):
   [0,64):            float scal[4]  (mu1, inv1, mu2, inv2)
   [1024, +131072):   float part1[4][8192]
   [132096, +12288):  float part2[3][1024]
   [144384, +49152):  bf16 Wf — fragment-ordered W
   [193536, +ROWS*128*2): bf16 total_gated (masked)                  */
#define P1_OFF 1024
#define P2_OFF 132096
#define WF_OFF 144384
#define X_OFF  193536

__device__ __forceinline__ float waveReduce(float v) {
#pragma unroll
  for (int off = 32; off > 0; off >>= 1) v += __shfl_down(v, off, 64);
  return v;
}

/* ------- K0: W (fp32, row-major 169x128) -> fragment-ordered bf16 ------- */
__global__ void k_wprep(const float* __restrict__ W, __bf16* __restrict__ Wf) {
  int t = blockIdx.x * 256 + threadIdx.x;
  if (t >= 6 * 8 * 64) return;
  int lane = t & 63, nt = (t >> 6) & 7, kc = t >> 9;
  int n  = nt * 16 + (lane & 15);
  int k0 = kc * 32 + (lane >> 4) * 8;
  bf16x8 v;
#pragma unroll
  for (int j = 0; j < 8; j++) {
    int k = k0 + j;
    v[j] = (k < KTOT) ? (__bf16)W[k * 128 + n] : (__bf16)0.f;
  }
  *reinterpret_cast<bf16x8*>(&Wf[(size_t)t * 8]) = v;
}

/* ---------------- K1: gather + concat + MFMA GEMM + mask + partial stats ------- */
__global__ __launch_bounds__(256, 8) void k_gemm(
    const float* __restrict__ atom, const float* __restrict__ nbr,
    const int* __restrict__ idx, const int* __restrict__ mask,
    const __bf16* __restrict__ Wf, const float* __restrict__ bias,
    float* __restrict__ part1, __bf16* __restrict__ xout)
{
  __shared__ __bf16 As[RPB * ASTR];   // 19200 B; C-tile (48x136 bf16) overlays it later
  __shared__ int    idx_s[RPB];
  __shared__ float  red[4][4];

  const int tid = threadIdx.x;
  const int g0  = blockIdx.x * NPB;
  const int bb  = (g0 >> 6) << 6;     // b * N_  (block never crosses a batch; 64%4==0)

  if (tid < RPB) idx_s[tid] = idx[g0 * M_ + tid];
  __syncthreads();

  // stage own-atom part, k in [0,64)  (3 iters)
  for (int e = tid; e < RPB * 16; e += 256) {
    int r = e >> 4, k4 = e & 15;
    int node = r / M_;
    float4 v = *(const float4*)&atom[(size_t)(g0 + node) * F_ + k4 * 4];
    __bf16 h[4] = {(__bf16)v.x, (__bf16)v.y, (__bf16)v.z, (__bf16)v.w};
    *reinterpret_cast<uint2*>(&As[r * ASTR + k4 * 4]) = *reinterpret_cast<uint2*>(h);
  }
  // stage gathered-atom part, k in [64,128)  (3 iters)
  for (int e = tid; e < RPB * 16; e += 256) {
    int r = e >> 4, k4 = e & 15;
    float4 v = *(const float4*)&atom[(size_t)(bb + idx_s[r]) * F_ + k4 * 4];
    __bf16 h[4] = {(__bf16)v.x, (__bf16)v.y, (__bf16)v.z, (__bf16)v.w};
    *reinterpret_cast<uint2*>(&As[r * ASTR + 64 + k4 * 4]) = *reinterpret_cast<uint2*>(h);
  }
  // stage nbr_fea part, k in [128,169): block slice is 48*41=1968 contiguous floats
  {
    const float* nb = &nbr[(size_t)(g0 * M_) * NF_];
    for (int e4 = tid; e4 < RPB * NF_ / 4; e4 += 256) {   // 492 float4s, 2 iters
      float4 v = *(const float4*)&nb[e4 * 4];
      float vv[4] = {v.x, v.y, v.z, v.w};
#pragma unroll
      for (int j = 0; j < 4; j++) {
        int e = e4 * 4 + j;
        int r = e / NF_, k = e - r * NF_;
        As[r * ASTR + 128 + k] = (__bf16)vv[j];
      }
    }
  }
  // zero pad k in [169,192)
  for (int e = tid; e < RPB * 32; e += 256) {
    int r = e >> 5, k = 168 + (e & 31);
    if (k >= KTOT) As[r * ASTR + k] = (__bf16)0.f;
  }
  __syncthreads();

  const int w    = tid >> 6;          // wave id: owns nt = {2w, 2w+1}
  const int lane = tid & 63;
  const int nlo  = lane & 15;
  const int quad = lane >> 4;

  f32x4 acc[3][2];
#pragma unroll
  for (int mt = 0; mt < 3; mt++)
#pragma unroll
    for (int j = 0; j < 2; j++) acc[mt][j] = (f32x4){0.f, 0.f, 0.f, 0.f};

#pragma unroll
  for (int kc = 0; kc < 6; kc++) {
    bf16x8 bf[2];
#pragma unroll
    for (int j = 0; j < 2; j++) {
      int nt = 2 * w + j;
      bf[j] = *reinterpret_cast<const bf16x8*>(&Wf[(size_t)(((kc * 8 + nt) * 64) + lane) * 8]);
    }
#pragma unroll
    for (int mt = 0; mt < 3; mt++) {
      bf16x8 af = *reinterpret_cast<const bf16x8*>(
          &As[(mt * 16 + nlo) * ASTR + kc * 32 + quad * 8]);
#pragma unroll
      for (int j = 0; j < 2; j++)
        acc[mt][j] = __builtin_amdgcn_mfma_f32_16x16x32_bf16(af, bf[j], acc[mt][j], 0, 0, 0);
    }
  }

  // ---- dump C tile (bias-added, bf16) into LDS for vectorized masked store ----
  float bv[2];
#pragma unroll
  for (int j = 0; j < 2; j++) bv[j] = bias[(2 * w + j) * 16 + nlo];

  __syncthreads();                    // all A-frag reads done; safe to overlay
  __bf16* Cs = As;
#pragma unroll
  for (int mt = 0; mt < 3; mt++)
#pragma unroll
    for (int reg = 0; reg < 4; reg++)
#pragma unroll
      for (int j = 0; j < 2; j++) {
        int row = mt * 16 + quad * 4 + reg;
        int col = (2 * w + j) * 16 + nlo;
        Cs[row * CSTR + col] = (__bf16)(acc[mt][j][reg] + bv[j]);
      }
  __syncthreads();

  // ---- vectorized mask + stats + store: 3 chunks of 8 per thread ----
  float s = 0.f, ss = 0.f, cz = 0.f, cm = 0.f;
#pragma unroll
  for (int i = 0; i < 3; i++) {
    int ch = tid + i * 256;           // 0..767
    int row = ch >> 4, c = ch & 15;
    size_t grow = (size_t)(g0 * M_) + row;
    bf16x8 yv = *reinterpret_cast<const bf16x8*>(&Cs[row * CSTR + c * 8]);
    const int4 mA = *(const int4*)&mask[grow * 128 + c * 8];
    const int4 mB = *(const int4*)&mask[grow * 128 + c * 8 + 4];
    int mv[8] = {mA.x, mA.y, mA.z, mA.w, mB.x, mB.y, mB.z, mB.w};
#pragma unroll
    for (int j = 0; j < 8; j++) {
      float y = (float)yv[j];
      if (!mv[j]) { y = 0.f; yv[j] = (__bf16)0.f; }
      s += y; ss += y * y;
      cz += (y != 0.f) ? 1.f : 0.f;
      cm += (float)mv[j];
    }
    *reinterpret_cast<bf16x8*>(&xout[grow * 128 + c * 8]) = yv;
  }

  float v0 = waveReduce(s), v1 = waveReduce(ss), v2 = waveReduce(cz), v3 = waveReduce(cm);
  if (lane == 0) { red[0][w] = v0; red[1][w] = v1; red[2][w] = v2; red[3][w] = v3; }
  __syncthreads();
  if (tid < 4)   // non-atomic partial store
    part1[tid * GBLK + blockIdx.x] =
        red[tid][0] + red[tid][1] + red[tid][2] + red[tid][3];
}

/* ------- R1: reduce part1 -> mu1, inv1 ------- */
__global__ __launch_bounds__(256) void k_red1(const float* __restrict__ part1,
                                              float* __restrict__ scal) {
  __shared__ double red[256][4];
  int t = threadIdx.x;
  double a[4] = {0.0, 0.0, 0.0, 0.0};
  for (int i = t; i < GBLK; i += 256)
#pragma unroll
    for (int q = 0; q < 4; q++) a[q] += (double)part1[q * GBLK + i];
#pragma unroll
  for (int q = 0; q < 4; q++) red[t][q] = a[q];
  __syncthreads();
  for (int s = 128; s > 0; s >>= 1) {
    if (t < s)
#pragma unroll
      for (int q = 0; q < 4; q++) red[t][q] += red[t + s][q];
    __syncthreads();
  }
  if (t == 0) {
    double S = red[0][0], SS = red[0][1], CNZ = red[0][2], CM = red[0][3];
    double mu = 0.0, var = 0.0;
    if (CNZ > 0.5) {
      mu = S / CNZ;
      var = (SS - 2.0 * mu * S + mu * mu * CM) / CNZ;
    }
    scal[0] = (float)mu;
    scal[1] = (float)(1.0 / sqrt(var + 1e-5));
  }
}

/* ------- K3: BN1-apply + sigmoid*softplus + sum over M + partial stats2 ------- */
__global__ __launch_bounds__(256) void k_act(
    const __bf16* __restrict__ x, const int* __restrict__ mask,
    const float* __restrict__ g1, const float* __restrict__ b1,
    const float* __restrict__ scal, float* __restrict__ part2,
    float* __restrict__ ns)
{
  __shared__ float red[3][4];
  int t = blockIdx.x * 256 + threadIdx.x;    // 0 .. NODES*8-1
  int g = t >> 3, o0 = (t & 7) * 8;

  float mu1 = scal[0], inv1 = scal[1];

  float kf[8], cf[8], kc[8], cc[8];
#pragma unroll
  for (int j = 0; j < 8; j++) {
    kf[j] = inv1 * g1[o0 + j];      cf[j] = b1[o0 + j]      - mu1 * kf[j];
    kc[j] = inv1 * g1[64 + o0 + j]; cc[j] = b1[64 + o0 + j] - mu1 * kc[j];
  }

  size_t base = (size_t)g * (M_ * 128) + o0;
  float ssum[8];
#pragma unroll
  for (int j = 0; j < 8; j++) ssum[j] = 0.f;

#pragma unroll
  for (int m = 0; m < M_; m++) {
    bf16x8 xf = *reinterpret_cast<const bf16x8*>(&x[base + m * 128]);
    bf16x8 xc = *reinterpret_cast<const bf16x8*>(&x[base + m * 128 + 64]);
#pragma unroll
    for (int j = 0; j < 8; j++) {
      float vf = (float)xf[j], vc = (float)xc[j];
      // x==0 <=> masked-out (stored exact 0); bn applies only where mask=1
      float yf = (vf != 0.f) ? fmaf(vf, kf[j], cf[j]) : 0.f;
      float yc = (vc != 0.f) ? fmaf(vc, kc[j], cc[j]) : 0.f;
      float sg = __builtin_amdgcn_rcpf(1.f + __expf(-yf));
      float sp = fmaxf(yc, 0.f) + __logf(1.f + __expf(-fabsf(yc)));
      ssum[j] += sg * sp;   // masked-out contributes sigmoid(0)*softplus(0), per ref
    }
  }

  const int4 mA = *(const int4*)&mask[(size_t)g * (M_ * 128) + o0];
  const int4 mB = *(const int4*)&mask[(size_t)g * (M_ * 128) + o0 + 4];
  int mn[8] = {mA.x, mA.y, mA.z, mA.w, mB.x, mB.y, mB.z, mB.w};
  float s = 0.f, ss2 = 0.f, c = 0.f;
  float v[8];
#pragma unroll
  for (int j = 0; j < 8; j++) {
    v[j] = mn[j] ? ssum[j] : 0.f;
    s += v[j]; ss2 += v[j] * v[j];
    c += (v[j] != 0.f) ? 1.f : 0.f;
  }
  *(float4*)&ns[(size_t)g * 64 + o0]     = (float4){v[0], v[1], v[2], v[3]};
  *(float4*)&ns[(size_t)g * 64 + o0 + 4] = (float4){v[4], v[5], v[6], v[7]};

  float v0 = waveReduce(s), v1 = waveReduce(ss2), v2 = waveReduce(c);
  int lane = threadIdx.x & 63, wid = threadIdx.x >> 6;
  if (lane == 0) { red[0][wid] = v0; red[1][wid] = v1; red[2][wid] = v2; }
  __syncthreads();
  if (threadIdx.x < 3)   // non-atomic partial store
    part2[threadIdx.x * ABLK + blockIdx.x] =
        red[threadIdx.x][0] + red[threadIdx.x][1] + red[threadIdx.x][2] + red[threadIdx.x][3];
}

/* ------- R2: reduce part2 -> mu2, inv2 ------- */
__global__ __launch_bounds__(256) void k_red2(const float* __restrict__ part2,
                                              float* __restrict__ scal) {
  __shared__ double red[256][3];
  int t = threadIdx.x;
  double a[3] = {0.0, 0.0, 0.0};
  for (int i = t; i < ABLK; i += 256)
#pragma unroll
    for (int q = 0; q < 3; q++) a[q] += (double)part2[q * ABLK + i];
#pragma unroll
  for (int q = 0; q < 3; q++) red[t][q] = a[q];
  __syncthreads();
  for (int s = 128; s > 0; s >>= 1) {
    if (t < s)
#pragma unroll
      for (int q = 0; q < 3; q++) red[t][q] += red[t + s][q];
    __syncthreads();
  }
  if (t == 0) {
    double S = red[0][0], SS = red[0][1], C = red[0][2];
    double mu = 0.0, var = 0.0;
    if (C > 0.5) {
      mu = S / C;
      var = (SS - 2.0 * mu * S + mu * mu * C) / C;
    }
    scal[2] = (float)mu;
    scal[3] = (float)(1.0 / sqrt(var + 1e-5));
  }
}

/* ---------------- K5: BN2-apply + residual softplus ---------------- */
__global__ __launch_bounds__(256) void k_out(
    const float* __restrict__ atom, const float* __restrict__ ns,
    const float* __restrict__ g2, const float* __restrict__ b2,
    const float* __restrict__ scal, float* __restrict__ out)
{
  int t = blockIdx.x * 256 + threadIdx.x;
  int g = t >> 3, o0 = (t & 7) * 8;
  float mu2 = scal[2], inv2 = scal[3];

  float4 n0 = *(const float4*)&ns[(size_t)g * 64 + o0];
  float4 n1 = *(const float4*)&ns[(size_t)g * 64 + o0 + 4];
  float4 a0 = *(const float4*)&atom[(size_t)g * 64 + o0];
  float4 a1 = *(const float4*)&atom[(size_t)g * 64 + o0 + 4];
  float nv[8] = {n0.x, n0.y, n0.z, n0.w, n1.x, n1.y, n1.z, n1.w};
  float av[8] = {a0.x, a0.y, a0.z, a0.w, a1.x, a1.y, a1.z, a1.w};
  float r[8];
#pragma unroll
  for (int j = 0; j < 8; j++) {
    r[j] = 0.f;
    if (nv[j] != 0.f) {   // ns != 0 <=> m_node == 1 (gated strictly > 0)
      float bn = (nv[j] - mu2) * inv2 * g2[o0 + j] + b2[o0 + j];
      float a = av[j] + bn;
      r[j] = fmaxf(a, 0.f) + __logf(1.f + __expf(-fabsf(a)));
    }
  }
  *(float4*)&out[(size_t)g * 64 + o0]     = (float4){r[0], r[1], r[2], r[3]};
  *(float4*)&out[(size_t)g * 64 + o0 + 4] = (float4){r[4], r[5], r[6], r[7]};
}

extern "C" void kernel_launch(void* const* d_in, const int* in_sizes, int n_in,
                              void* d_out, int out_size, void* d_ws, size_t ws_size,
                              hipStream_t stream)
{
  const float* atom = (const float*)d_in[0];
  const float* nbr  = (const float*)d_in[1];
  const float* W    = (const float*)d_in[2];
  const float* bias = (const float*)d_in[3];
  const float* g1   = (const float*)d_in[4];
  const float* b1   = (const float*)d_in[5];
  const float* g2   = (const float*)d_in[6];
  const float* b2   = (const float*)d_in[7];
  const int*   idx  = (const int*)d_in[8];
  const int*   mask = (const int*)d_in[9];
  float* out = (float*)d_out;

  char* ws = (char*)d_ws;
  float*  scal  = (float*)ws;
  float*  part1 = (float*)(ws + P1_OFF);
  float*  part2 = (float*)(ws + P2_OFF);
  __bf16* Wf    = (__bf16*)(ws + WF_OFF);
  __bf16* x     = (__bf16*)(ws + X_OFF);
  float* ns = out;   // reuse d_out: k_act writes all of it, k_out rewrites in place

  k_wprep<<<12, 256, 0, stream>>>(W, Wf);
  k_gemm<<<GBLK, 256, 0, stream>>>(atom, nbr, idx, mask, Wf, bias, part1, x);
  k_red1<<<1, 256, 0, stream>>>(part1, scal);
  k_act<<<(NODES * 8) / 256, 256, 0, stream>>>(x, mask, g1, b1, scal, part2, ns);
  k_red2<<<1, 256, 0, stream>>>(part2, scal);
  k_out<<<(NODES * 8) / 256, 256, 0, stream>>>(atom, ns, g2, b2, scal, out);
}